// Round 1
// baseline (294.343 us; speedup 1.0000x reference)
//
#include <hip/hip_runtime.h>

#define INPUT_DIM 16
#define COLS 273                   // 1 + 16 + 256
#define ROWS_PER_BLOCK 16
#define FLOATS_PER_BLOCK (ROWS_PER_BLOCK * COLS)   // 4368
#define VEC4_PER_BLOCK (FLOATS_PER_BLOCK / 4)      // 1092

// scales: RRD = d**0.25 = 2  -> 1/RRD = 0.5
//         second-order scale = 1/(sqrt(2)*sqrt(d)) = 1/(4*sqrt(2))
#define S1 0.5f
#define S2 0.17677669529663687f

__global__ __launch_bounds__(256)
void taylor_exp_kernel(const float* __restrict__ x, float* __restrict__ out)
{
    __shared__ float xs[ROWS_PER_BLOCK * INPUT_DIM];   // 16 rows x 16 floats = 1 KiB

    const int tid = threadIdx.x;
    const long long rowBase = (long long)blockIdx.x * ROWS_PER_BLOCK;

    // one coalesced 1 KiB load: 256 threads load 256 floats
    xs[tid] = x[rowBase * INPUT_DIM + tid];
    __syncthreads();

    float4* __restrict__ out4 =
        (float4*)(out + rowBase * COLS);   // byte offset bid*17472, 16B-aligned

    #pragma unroll 1
    for (int v = tid; v < VEC4_PER_BLOCK; v += 256) {
        float vals[4];
        #pragma unroll
        for (int k = 0; k < 4; ++k) {
            const int g  = 4 * v + k;          // 0..4367 within block
            const int rl = g / COLS;           // local row 0..15 (magic-mul)
            const int c  = g - rl * COLS;      // column 0..272
            const float* xr = &xs[rl * INPUT_DIM];
            float val;
            if (c == 0) {
                val = 1.0f;
            } else if (c <= INPUT_DIM) {
                val = xr[c - 1] * S1;
            } else {
                const int t = c - (INPUT_DIM + 1);
                val = xr[t >> 4] * xr[t & 15] * S2;
            }
            vals[k] = val;
        }
        float4 r;
        r.x = vals[0]; r.y = vals[1]; r.z = vals[2]; r.w = vals[3];
        out4[v] = r;
    }
}

extern "C" void kernel_launch(void* const* d_in, const int* in_sizes, int n_in,
                              void* d_out, int out_size, void* d_ws, size_t ws_size,
                              hipStream_t stream)
{
    const float* x = (const float*)d_in[0];
    float* out = (float*)d_out;

    const int nrows  = in_sizes[0] / INPUT_DIM;        // 262144
    const int blocks = nrows / ROWS_PER_BLOCK;         // 16384

    taylor_exp_kernel<<<blocks, 256, 0, stream>>>(x, out);
}